// Round 3
// baseline (2654.146 us; speedup 1.0000x reference)
//
#include <hip/hip_runtime.h>

#define CIN   256
#define COUT  512
#define HW    1024     // H*W = 32*32
#define ITERS 20

typedef __attribute__((ext_vector_type(8))) short bf16x8;
typedef __attribute__((ext_vector_type(4))) short bf16x4;
typedef __attribute__((ext_vector_type(4))) float f32x4;

__device__ __forceinline__ unsigned short f2b(float x) {
  unsigned b = __builtin_bit_cast(unsigned, x);
  unsigned r = (b + 0x7FFFu + ((b >> 16) & 1u)) >> 16;   // RNE
  return (unsigned short)r;
}
__device__ __forceinline__ float b2f(unsigned short u) {
  return __builtin_bit_cast(float, (unsigned)u << 16);
}

// Pre-swizzle weight into MFMA A-operand fragment layouts (bf16).
// w1 (GEMM1T A = W^T): tile(ct,jkt): val = w[(32jkt+8q+i)*CIN + 16ct+col]
//   layout [ct:16][jkt:16][lane:64][i:8]
// w2 (GEMM2T A = W):   tile(jt,ckt): val = w[(16jt+col)*CIN + 32ckt+8q+i]
//   layout [jt:32][ckt:8][lane:64][i:8]
__global__ __launch_bounds__(256) void prep_weights(const float* __restrict__ w,
                                                    unsigned short* __restrict__ w1,
                                                    unsigned short* __restrict__ w2) {
  int f = blockIdx.x * 256 + threadIdx.x;   // [0, 131072)
  {
    int i = f & 7, lane = (f >> 3) & 63, jkt = (f >> 9) & 15, ct = f >> 13;
    int c = ct * 16 + (lane & 15);
    int j = jkt * 32 + (lane >> 4) * 8 + i;
    w1[f] = f2b(w[j * CIN + c]);
  }
  {
    int i = f & 7, lane = (f >> 3) & 63, ckt = (f >> 9) & 7, jt = f >> 12;
    int j = jt * 16 + (lane & 15);
    int c = ckt * 32 + (lane >> 4) * 8 + i;
    w2[f] = f2b(w[j * CIN + c]);
  }
}

// Fused NNMF, transposed-GEMM layout. 1 WG = 32 pixels, 20 iters on-chip.
// LDS = 32KB(hB) + 8KB(yF half-c) = 40960 -> 4 blocks/CU (single round).
// h state fp32 in regs (tT C-layout: m=lane&15 fixed per lane).
// Cross-wave row-sums via global d_ws (volatile, L2).
__global__ __launch_bounds__(256, 4) void nnmf_kernel(const float* __restrict__ xin,
                                                      const unsigned short* __restrict__ w1,
                                                      const unsigned short* __restrict__ w2,
                                                      float* __restrict__ redws_all,
                                                      float* __restrict__ out) {
  __shared__ __align__(16) unsigned short hB[2 * 16 * 64 * 8]; // 32 KB: h bf16 B-frags
  __shared__ __align__(16) unsigned short yF[2 * 4 * 64 * 8];  // 8 KB: y bf16 B-frags (half-c)

  const int tid  = threadIdx.x;
  const int wave = tid >> 6;
  const int lane = tid & 63;
  const int quad = lane >> 4;
  const int col  = lane & 15;

  const int wg     = blockIdx.x;
  const int bb     = wg >> 5;
  const int hwbase = (wg & 31) * 32;
  const float* xbase = xin + (size_t)bb * (CIN * HW) + hwbase;
  float* redws = redws_all + (size_t)wg * 128;   // [m:32][wave:4]

  // ---- stage x into hB region as u16 [c:256][m:32], coalesced ----
  {
    int m  = tid & 31;
    int c0 = tid >> 5;
#pragma unroll
    for (int g = 0; g < 32; ++g) {
      int c = c0 + (g << 3);
      hB[c * 32 + m] = f2b(xbase[c * HW + m]);
    }
  }
  __syncthreads();

  // ---- gather x into packed regs: xpk[mt][ci][p] = {x(c0), x(c0+1)} ----
  // lane's y-transform coords: m = 16mt+col, c = 16(wave+4ci)+4quad+2p+e
  unsigned xpk[2][4][2];
#pragma unroll
  for (int mt = 0; mt < 2; ++mt)
#pragma unroll
    for (int ci = 0; ci < 4; ++ci)
#pragma unroll
      for (int p = 0; p < 2; ++p) {
        int c = ((wave + (ci << 2)) << 4) + (quad << 2) + (p << 1);
        int m = (mt << 4) + col;
        unsigned lo = hB[c * 32 + m];
        unsigned hi = hB[(c + 1) * 32 + m];
        xpk[mt][ci][p] = lo | (hi << 16);
      }
  __syncthreads();

  // ---- init hB = bf16(1/512) everywhere (exact) ----
  {
    unsigned* p32 = (unsigned*)hB;
#pragma unroll
    for (int g = 0; g < 32; ++g) p32[tid + (g << 8)] = 0x3B003B00u;
  }
  __syncthreads();

  // persistent h (unnormalized), tT C-layout: m=16mt+col, j=128w+16n+4quad+r
  f32x4 hreg[2][8];
#pragma unroll
  for (int mt = 0; mt < 2; ++mt)
#pragma unroll
    for (int n = 0; n < 8; ++n)
#pragma unroll
      for (int r = 0; r < 4; ++r) hreg[mt][n][r] = 1.0f / 512.0f;

  for (int it = 0; it < ITERS; ++it) {
    // ---- hoist row-sum loads (volatile, written by all waves last iter) ----
    float rs[2][4];
    if (it) {
      volatile const float* rv = redws;
#pragma unroll
      for (int mt = 0; mt < 2; ++mt)
#pragma unroll
        for (int k = 0; k < 4; ++k) rs[mt][k] = rv[((mt << 4) + col) * 4 + k];
    }

    // ===== GEMM1T: recT[c][m] = sum_j W^T[c][j] h[m][j]; wave ct = w+4ci =====
    f32x4 acc1[2][4];
#pragma unroll
    for (int mt = 0; mt < 2; ++mt)
#pragma unroll
      for (int ci = 0; ci < 4; ++ci)
#pragma unroll
        for (int r = 0; r < 4; ++r) acc1[mt][ci][r] = 0.0f;

#pragma unroll 4
    for (int jkt = 0; jkt < 16; ++jkt) {
      bf16x8 b0 = *(const bf16x8*)(hB + ((jkt) * 64 + lane) * 8);
      bf16x8 b1 = *(const bf16x8*)(hB + ((16 + jkt) * 64 + lane) * 8);
#pragma unroll
      for (int ci = 0; ci < 4; ++ci) {
        int ct = wave + (ci << 2);
        bf16x8 a = *(const bf16x8*)(w1 + ((ct * 16 + jkt) * 64 + lane) * 8);
        acc1[0][ci] = __builtin_amdgcn_mfma_f32_16x16x32_bf16(a, b0, acc1[0][ci], 0, 0, 0);
        acc1[1][ci] = __builtin_amdgcn_mfma_f32_16x16x32_bf16(a, b1, acc1[1][ci], 0, 0, 0);
      }
    }

    float invv[2];
    if (it) {
#pragma unroll
      for (int mt = 0; mt < 2; ++mt)
        invv[mt] = __builtin_amdgcn_rcpf(rs[mt][0] + rs[mt][1] + rs[mt][2] + rs[mt][3] + 1e-19f);
    } else {
      invv[0] = invv[1] = 1.0f;
    }

    // ---- y half0 (ci 0,1 -> ckt 0..3): b64 frag writes ----
#pragma unroll
    for (int ci = 0; ci < 2; ++ci) {
      int ct = wave + (ci << 2);
      int ckh = (ct >> 1) & 3;
      int lane_t = col | ((((ct & 1) << 1) + (quad >> 1)) << 4);
      int i0 = (quad & 1) << 2;
#pragma unroll
      for (int mt = 0; mt < 2; ++mt) {
        bf16x4 v;
#pragma unroll
        for (int r = 0; r < 4; ++r) {
          float rec = __builtin_fmaf(invv[mt], acc1[mt][ci][r], 1e-20f);
          float xv  = b2f((unsigned short)(xpk[mt][ci][r >> 1] >> ((r & 1) << 4)));
          v[r] = (short)f2b(xv * __builtin_amdgcn_rcpf(rec));
        }
        *(bf16x4*)(yF + ((mt * 4 + ckh) * 64 + lane_t) * 8 + i0) = v;
      }
    }
    __syncthreads();   // bar1: yF half0 ready

    // ===== GEMM2T half a: tT[j][m], ckt 0..3 =====
    f32x4 acc2[2][8];
#pragma unroll
    for (int mt = 0; mt < 2; ++mt)
#pragma unroll
      for (int n = 0; n < 8; ++n)
#pragma unroll
        for (int r = 0; r < 4; ++r) acc2[mt][n][r] = 0.0f;

#pragma unroll
    for (int ckt = 0; ckt < 4; ++ckt) {
      bf16x8 b0 = *(const bf16x8*)(yF + ((ckt) * 64 + lane) * 8);
      bf16x8 b1 = *(const bf16x8*)(yF + ((4 + ckt) * 64 + lane) * 8);
#pragma unroll
      for (int n = 0; n < 8; ++n) {
        int jt = (wave << 3) + n;
        bf16x8 a = *(const bf16x8*)(w2 + ((jt * 8 + ckt) * 64 + lane) * 8);
        acc2[0][n] = __builtin_amdgcn_mfma_f32_16x16x32_bf16(a, b0, acc2[0][n], 0, 0, 0);
        acc2[1][n] = __builtin_amdgcn_mfma_f32_16x16x32_bf16(a, b1, acc2[1][n], 0, 0, 0);
      }
    }
    __syncthreads();   // bar2: yF half0 consumed

    // ---- y half1 (ci 2,3 -> ckt 4..7) ----
#pragma unroll
    for (int ci = 2; ci < 4; ++ci) {
      int ct = wave + (ci << 2);
      int ckh = (ct >> 1) & 3;
      int lane_t = col | ((((ct & 1) << 1) + (quad >> 1)) << 4);
      int i0 = (quad & 1) << 2;
#pragma unroll
      for (int mt = 0; mt < 2; ++mt) {
        bf16x4 v;
#pragma unroll
        for (int r = 0; r < 4; ++r) {
          float rec = __builtin_fmaf(invv[mt], acc1[mt][ci][r], 1e-20f);
          float xv  = b2f((unsigned short)(xpk[mt][ci][r >> 1] >> ((r & 1) << 4)));
          v[r] = (short)f2b(xv * __builtin_amdgcn_rcpf(rec));
        }
        *(bf16x4*)(yF + ((mt * 4 + ckh) * 64 + lane_t) * 8 + i0) = v;
      }
    }
    __syncthreads();   // bar3: yF half1 ready

    // ===== GEMM2T half b: ckt 4..7 =====
#pragma unroll
    for (int ckt = 4; ckt < 8; ++ckt) {
      int ckh = ckt & 3;
      bf16x8 b0 = *(const bf16x8*)(yF + ((ckh) * 64 + lane) * 8);
      bf16x8 b1 = *(const bf16x8*)(yF + ((4 + ckh) * 64 + lane) * 8);
#pragma unroll
      for (int n = 0; n < 8; ++n) {
        int jt = (wave << 3) + n;
        bf16x8 a = *(const bf16x8*)(w2 + ((jt * 8 + ckt) * 64 + lane) * 8);
        acc2[0][n] = __builtin_amdgcn_mfma_f32_16x16x32_bf16(a, b0, acc2[0][n], 0, 0, 0);
        acc2[1][n] = __builtin_amdgcn_mfma_f32_16x16x32_bf16(a, b1, acc2[1][n], 0, 0, 0);
      }
    }

    // ===== h_un_new = (h_un * inv) * t ; psum ; write hB(b64) + red =====
    float psum[2] = {0.0f, 0.0f};
#pragma unroll
    for (int mt = 0; mt < 2; ++mt)
#pragma unroll
      for (int n = 0; n < 8; ++n) {
        bf16x4 v;
#pragma unroll
        for (int r = 0; r < 4; ++r) {
          float hn = hreg[mt][n][r] * invv[mt] * acc2[mt][n][r];
          hreg[mt][n][r] = hn;
          psum[mt] += hn;
          v[r] = (short)f2b(hn);
        }
        if (it < ITERS - 1) {
          // j = 128w+16n+4quad+r: jkt = 4w+(n>>1), quad_t = 2(n&1)+(quad>>1), i0 = 4(quad&1)
          int jkt = (wave << 2) + (n >> 1);
          int lane_t = col | ((((n & 1) << 1) + (quad >> 1)) << 4);
          int i0 = (quad & 1) << 2;
          *(bf16x4*)(hB + ((mt * 16 + jkt) * 64 + lane_t) * 8 + i0) = v;
        }
      }
    // reduce across quads (lanes col, col+16, col+32, col+48)
#pragma unroll
    for (int mt = 0; mt < 2; ++mt) {
      psum[mt] += __shfl_xor(psum[mt], 16, 64);
      psum[mt] += __shfl_xor(psum[mt], 32, 64);
    }
    if (quad == 0) {
      volatile float* rv = redws;
#pragma unroll
      for (int mt = 0; mt < 2; ++mt) rv[((mt << 4) + col) * 4 + wave] = psum[mt];
    }
    __syncthreads();   // bar4: hB + red ready (vmcnt drained by barrier)
  }

  // ---- final normalize + store ----
  float invf[2];
  {
    volatile const float* rv = redws;
#pragma unroll
    for (int mt = 0; mt < 2; ++mt) {
      float s = 0.0f;
#pragma unroll
      for (int k = 0; k < 4; ++k) s += rv[((mt << 4) + col) * 4 + k];
      invf[mt] = __builtin_amdgcn_rcpf(s + 1e-19f);
    }
  }
  float* obase = out + (size_t)bb * (COUT * HW) + hwbase;
#pragma unroll
  for (int mt = 0; mt < 2; ++mt)
#pragma unroll
    for (int n = 0; n < 8; ++n) {
      int j = (wave << 7) + (n << 4) + (quad << 2);
#pragma unroll
      for (int r = 0; r < 4; ++r)
        obase[(size_t)(j + r) * HW + (mt << 4) + col] = hreg[mt][n][r] * invf[mt];
    }
}

extern "C" void kernel_launch(void* const* d_in, const int* in_sizes, int n_in,
                              void* d_out, int out_size, void* d_ws, size_t ws_size,
                              hipStream_t stream) {
  const float* x = (const float*)d_in[0];   // [32,256,32,32]
  const float* w = (const float*)d_in[1];   // [512,256]
  unsigned short* w1 = (unsigned short*)d_ws;           // 256 KB
  unsigned short* w2 = w1 + COUT * CIN;                 // 256 KB
  float* red = (float*)(w2 + COUT * CIN);               // 512 KB
  float* out = (float*)d_out;

  prep_weights<<<dim3(512), dim3(256), 0, stream>>>(w, w1, w2);
  nnmf_kernel<<<dim3(32768 / 32), dim3(256), 0, stream>>>(x, w1, w2, red, out);
}

// Round 4
// 2016.204 us; speedup vs baseline: 1.3164x; 1.3164x over previous
//
#include <hip/hip_runtime.h>

#define CIN   256
#define COUT  512
#define HW    1024     // H*W = 32*32
#define ITERS 20

typedef __attribute__((ext_vector_type(8))) short bf16x8;
typedef __attribute__((ext_vector_type(4))) short bf16x4;
typedef __attribute__((ext_vector_type(4))) float f32x4;

__device__ __forceinline__ unsigned short f2b(float x) {
  unsigned b = __builtin_bit_cast(unsigned, x);
  unsigned r = (b + 0x7FFFu + ((b >> 16) & 1u)) >> 16;   // RNE
  return (unsigned short)r;
}
__device__ __forceinline__ float b2f(unsigned short u) {
  return __builtin_bit_cast(float, (unsigned)u << 16);
}

// Pre-swizzle weight into MFMA A-operand fragment layouts (bf16).
// w1 (GEMM1T A = W^T): [ct:16][jkt:16][lane:64][i:8], val = w[(32jkt+8q+i)*CIN + 16ct+col]
// w2 (GEMM2T A = W):   [jt:32][ckt:8][lane:64][i:8],  val = w[(16jt+col)*CIN + 32ckt+8q+i]
__global__ __launch_bounds__(256) void prep_weights(const float* __restrict__ w,
                                                    unsigned short* __restrict__ w1,
                                                    unsigned short* __restrict__ w2) {
  int f = blockIdx.x * 256 + threadIdx.x;   // [0, 131072)
  {
    int i = f & 7, lane = (f >> 3) & 63, jkt = (f >> 9) & 15, ct = f >> 13;
    int c = ct * 16 + (lane & 15);
    int j = jkt * 32 + (lane >> 4) * 8 + i;
    w1[f] = f2b(w[j * CIN + c]);
  }
  {
    int i = f & 7, lane = (f >> 3) & 63, ckt = (f >> 9) & 7, jt = f >> 12;
    int j = jt * 16 + (lane & 15);
    int c = ckt * 32 + (lane >> 4) * 8 + i;
    w2[f] = f2b(w[j * CIN + c]);
  }
}

// Fused NNMF, transposed-GEMM layout. 1 WG = 32 pixels, 20 iters on-chip.
// LDS = 32KB(hB) + 8KB(yF half-c) = 40960 B -> 4 blocks/CU, 16 waves/CU.
// h state lives ONLY in hB (bf16, unnormalized); per-lane exclusive b64 RMW.
// Register peak ~105 (acc2 64 in AGPR + xpk 16 + temps) -> no spill at 128 cap.
// Cross-wave row-sums via global d_ws (volatile, L2; hoisted under GEMM1).
__global__ __launch_bounds__(256, 4) void nnmf_kernel(const float* __restrict__ xin,
                                                      const unsigned short* __restrict__ w1,
                                                      const unsigned short* __restrict__ w2,
                                                      float* __restrict__ redws_all,
                                                      float* __restrict__ out) {
  __shared__ __align__(16) unsigned short hB[2 * 16 * 64 * 8]; // 32 KB
  __shared__ __align__(16) unsigned short yF[2 * 4 * 64 * 8];  // 8 KB

  const int tid  = threadIdx.x;
  const int wave = tid >> 6;
  const int lane = tid & 63;
  const int quad = lane >> 4;
  const int col  = lane & 15;

  const int wg     = blockIdx.x;
  const int bb     = wg >> 5;
  const int hwbase = (wg & 31) * 32;
  const float* xbase = xin + (size_t)bb * (CIN * HW) + hwbase;
  float* redws = redws_all + (size_t)wg * 128;   // [m:32][wave:4]

  // ---- stage x into hB region as u16 [c:256][m:32], coalesced ----
  {
    int m  = tid & 31;
    int c0 = tid >> 5;
#pragma unroll
    for (int g = 0; g < 32; ++g) {
      int c = c0 + (g << 3);
      hB[c * 32 + m] = f2b(xbase[c * HW + m]);
    }
  }
  __syncthreads();

  // ---- gather x into packed regs: xpk[mt][ci][p], coords m=16mt+col, c=16(wave+4ci)+4quad+2p+e ----
  unsigned xpk[2][4][2];
#pragma unroll
  for (int mt = 0; mt < 2; ++mt)
#pragma unroll
    for (int ci = 0; ci < 4; ++ci)
#pragma unroll
      for (int p = 0; p < 2; ++p) {
        int c = ((wave + (ci << 2)) << 4) + (quad << 2) + (p << 1);
        int m = (mt << 4) + col;
        unsigned lo = hB[c * 32 + m];
        unsigned hi = hB[(c + 1) * 32 + m];
        xpk[mt][ci][p] = lo | (hi << 16);
      }
  __syncthreads();

  // ---- init hB = bf16(1/512) everywhere (exact; row-sum = 1 -> inv0 = 1) ----
  {
    unsigned* p32 = (unsigned*)hB;
#pragma unroll
    for (int g = 0; g < 32; ++g) p32[tid + (g << 8)] = 0x3B003B00u;
  }
  __syncthreads();

  f32x4 acc2[2][8];   // GEMM2 acc; final iter leaves fp32 h here
  float invv[2];

  for (int it = 0; it < ITERS; ++it) {
    // ---- hoisted row-sum loads (consumed after GEMM1) ----
    float rs[2][4];
    if (it) {
      volatile const float* rv = redws;
#pragma unroll
      for (int mt = 0; mt < 2; ++mt)
#pragma unroll
        for (int k = 0; k < 4; ++k) rs[mt][k] = rv[((mt << 4) + col) * 4 + k];
    }

    // ===== GEMM1T: recT[c][m] = sum_j W^T[c][j] h[m][j]; wave ct = wave+4ci =====
    f32x4 acc1[2][4];
#pragma unroll
    for (int mt = 0; mt < 2; ++mt)
#pragma unroll
      for (int ci = 0; ci < 4; ++ci)
#pragma unroll
        for (int r = 0; r < 4; ++r) acc1[mt][ci][r] = 0.0f;

#pragma unroll 4
    for (int jkt = 0; jkt < 16; ++jkt) {
      bf16x8 b0 = *(const bf16x8*)(hB + ((jkt) * 64 + lane) * 8);
      bf16x8 b1 = *(const bf16x8*)(hB + ((16 + jkt) * 64 + lane) * 8);
#pragma unroll
      for (int ci = 0; ci < 4; ++ci) {
        int ct = wave + (ci << 2);
        bf16x8 a = *(const bf16x8*)(w1 + ((ct * 16 + jkt) * 64 + lane) * 8);
        acc1[0][ci] = __builtin_amdgcn_mfma_f32_16x16x32_bf16(a, b0, acc1[0][ci], 0, 0, 0);
        acc1[1][ci] = __builtin_amdgcn_mfma_f32_16x16x32_bf16(a, b1, acc1[1][ci], 0, 0, 0);
      }
    }

    if (it) {
#pragma unroll
      for (int mt = 0; mt < 2; ++mt)
        invv[mt] = __builtin_amdgcn_rcpf(rs[mt][0] + rs[mt][1] + rs[mt][2] + rs[mt][3] + 1e-19f);
    } else {
      invv[0] = invv[1] = 1.0f;
    }

    // ---- y half0 (ci 0,1 -> ckt 0..3): b64 frag writes ----
#pragma unroll
    for (int ci = 0; ci < 2; ++ci) {
      int ct = wave + (ci << 2);
      int ckh = (ct >> 1) & 3;
      int lane_t = col | ((((ct & 1) << 1) + (quad >> 1)) << 4);
      int i0 = (quad & 1) << 2;
#pragma unroll
      for (int mt = 0; mt < 2; ++mt) {
        bf16x4 v;
#pragma unroll
        for (int r = 0; r < 4; ++r) {
          float rec = __builtin_fmaf(invv[mt], acc1[mt][ci][r], 1e-20f);
          float xv  = b2f((unsigned short)(xpk[mt][ci][r >> 1] >> ((r & 1) << 4)));
          v[r] = (short)f2b(xv * __builtin_amdgcn_rcpf(rec));
        }
        *(bf16x4*)(yF + ((mt * 4 + ckh) * 64 + lane_t) * 8 + i0) = v;
      }
    }
    __syncthreads();   // bar1: yF half0 ready (also: all waves done reading hB)

    // ===== GEMM2T half a (ckt 0..3) =====
#pragma unroll
    for (int mt = 0; mt < 2; ++mt)
#pragma unroll
      for (int n = 0; n < 8; ++n)
#pragma unroll
        for (int r = 0; r < 4; ++r) acc2[mt][n][r] = 0.0f;

#pragma unroll
    for (int ckt = 0; ckt < 4; ++ckt) {
      bf16x8 b0 = *(const bf16x8*)(yF + ((ckt) * 64 + lane) * 8);
      bf16x8 b1 = *(const bf16x8*)(yF + ((4 + ckt) * 64 + lane) * 8);
#pragma unroll
      for (int n = 0; n < 8; ++n) {
        int jt = (wave << 3) + n;
        bf16x8 a = *(const bf16x8*)(w2 + ((jt * 8 + ckt) * 64 + lane) * 8);
        acc2[0][n] = __builtin_amdgcn_mfma_f32_16x16x32_bf16(a, b0, acc2[0][n], 0, 0, 0);
        acc2[1][n] = __builtin_amdgcn_mfma_f32_16x16x32_bf16(a, b1, acc2[1][n], 0, 0, 0);
      }
    }
    __syncthreads();   // bar2: yF half0 consumed

    // ---- y half1 (ci 2,3 -> ckt 4..7) ----
#pragma unroll
    for (int ci = 2; ci < 4; ++ci) {
      int ct = wave + (ci << 2);
      int ckh = (ct >> 1) & 3;
      int lane_t = col | ((((ct & 1) << 1) + (quad >> 1)) << 4);
      int i0 = (quad & 1) << 2;
#pragma unroll
      for (int mt = 0; mt < 2; ++mt) {
        bf16x4 v;
#pragma unroll
        for (int r = 0; r < 4; ++r) {
          float rec = __builtin_fmaf(invv[mt], acc1[mt][ci][r], 1e-20f);
          float xv  = b2f((unsigned short)(xpk[mt][ci][r >> 1] >> ((r & 1) << 4)));
          v[r] = (short)f2b(xv * __builtin_amdgcn_rcpf(rec));
        }
        *(bf16x4*)(yF + ((mt * 4 + ckh) * 64 + lane_t) * 8 + i0) = v;
      }
    }
    __syncthreads();   // bar3: yF half1 ready

    // ===== GEMM2T half b (ckt 4..7) =====
#pragma unroll
    for (int ckt = 4; ckt < 8; ++ckt) {
      int ckh = ckt & 3;
      bf16x8 b0 = *(const bf16x8*)(yF + ((ckh) * 64 + lane) * 8);
      bf16x8 b1 = *(const bf16x8*)(yF + ((4 + ckh) * 64 + lane) * 8);
#pragma unroll
      for (int n = 0; n < 8; ++n) {
        int jt = (wave << 3) + n;
        bf16x8 a = *(const bf16x8*)(w2 + ((jt * 8 + ckt) * 64 + lane) * 8);
        acc2[0][n] = __builtin_amdgcn_mfma_f32_16x16x32_bf16(a, b0, acc2[0][n], 0, 0, 0);
        acc2[1][n] = __builtin_amdgcn_mfma_f32_16x16x32_bf16(a, b1, acc2[1][n], 0, 0, 0);
      }
    }

    // ===== h-update: b64 RMW on own exclusive slice of hB =====
    // j = 128w+16n+4q+r -> jkt=4w+(n>>1), lane_t=col|((2(n&1)+(q>>1))<<4), i0=4(q&1)
    float psum[2] = {0.0f, 0.0f};
#pragma unroll
    for (int mt = 0; mt < 2; ++mt)
#pragma unroll
      for (int n = 0; n < 8; ++n) {
        int jkt = (wave << 2) + (n >> 1);
        int lane_t = col | ((((n & 1) << 1) + (quad >> 1)) << 4);
        int i0 = (quad & 1) << 2;
        unsigned short* hp = hB + (((mt << 4) + jkt) * 64 + lane_t) * 8 + i0;
        bf16x4 ho = *(const bf16x4*)hp;
        bf16x4 v;
#pragma unroll
        for (int r = 0; r < 4; ++r) {
          float hn = b2f((unsigned short)ho[r]) * invv[mt] * acc2[mt][n][r];
          acc2[mt][n][r] = hn;           // fp32 copy (final-iter output path)
          psum[mt] += hn;
          v[r] = (short)f2b(hn);
        }
        if (it < ITERS - 1) *(bf16x4*)hp = v;
      }
    // reduce across quads (same col = same pixel m)
#pragma unroll
    for (int mt = 0; mt < 2; ++mt) {
      psum[mt] += __shfl_xor(psum[mt], 16, 64);
      psum[mt] += __shfl_xor(psum[mt], 32, 64);
    }
    if (quad == 0) {
      volatile float* rv = redws;
#pragma unroll
      for (int mt = 0; mt < 2; ++mt) rv[((mt << 4) + col) * 4 + wave] = psum[mt];
    }
    __syncthreads();   // bar4: hB + red drained (vmcnt(0) before s_barrier)
  }

  // ---- final normalize from fp32 acc2; store ----
  float invf[2];
  {
    volatile const float* rv = redws;
#pragma unroll
    for (int mt = 0; mt < 2; ++mt) {
      float s = 0.0f;
#pragma unroll
      for (int k = 0; k < 4; ++k) s += rv[((mt << 4) + col) * 4 + k];
      invf[mt] = __builtin_amdgcn_rcpf(s + 1e-19f);
    }
  }
  float* obase = out + (size_t)bb * (COUT * HW) + hwbase;
#pragma unroll
  for (int mt = 0; mt < 2; ++mt)
#pragma unroll
    for (int n = 0; n < 8; ++n) {
      int j = (wave << 7) + (n << 4) + (quad << 2);
#pragma unroll
      for (int r = 0; r < 4; ++r)
        obase[(size_t)(j + r) * HW + (mt << 4) + col] = acc2[mt][n][r] * invf[mt];
    }
}

extern "C" void kernel_launch(void* const* d_in, const int* in_sizes, int n_in,
                              void* d_out, int out_size, void* d_ws, size_t ws_size,
                              hipStream_t stream) {
  const float* x = (const float*)d_in[0];   // [32,256,32,32]
  const float* w = (const float*)d_in[1];   // [512,256]
  unsigned short* w1 = (unsigned short*)d_ws;           // 256 KB
  unsigned short* w2 = w1 + COUT * CIN;                 // 256 KB
  float* red = (float*)(w2 + COUT * CIN);               // 512 KB
  float* out = (float*)d_out;

  prep_weights<<<dim3(512), dim3(256), 0, stream>>>(w, w1, w2);
  nnmf_kernel<<<dim3(32768 / 32), dim3(256), 0, stream>>>(x, w1, w2, red, out);
}

// Round 5
// 1523.612 us; speedup vs baseline: 1.7420x; 1.3233x over previous
//
#include <hip/hip_runtime.h>

#define CIN   256
#define COUT  512
#define HW    1024     // H*W = 32*32
#define ITERS 20

typedef __attribute__((ext_vector_type(8))) short bf16x8;
typedef __attribute__((ext_vector_type(4))) short bf16x4;
typedef __attribute__((ext_vector_type(4))) float f32x4;

__device__ __forceinline__ unsigned short f2b(float x) {
  unsigned b = __builtin_bit_cast(unsigned, x);
  unsigned r = (b + 0x7FFFu + ((b >> 16) & 1u)) >> 16;   // RNE
  return (unsigned short)r;
}
__device__ __forceinline__ float b2f(unsigned short u) {
  return __builtin_bit_cast(float, (unsigned)u << 16);
}

// Pre-swizzle weight into MFMA A-operand fragment layouts (bf16).
// w1 (GEMM1T A = W^T): [ct:16][jkt:16][lane:64][i:8], val = w[(32jkt+8q+i)*CIN + 16ct+col]
// w2 (GEMM2T A = W):   [jt:32][ckt:8][lane:64][i:8],  val = w[(16jt+col)*CIN + 32ckt+8q+i]
__global__ __launch_bounds__(256) void prep_weights(const float* __restrict__ w,
                                                    unsigned short* __restrict__ w1,
                                                    unsigned short* __restrict__ w2) {
  int f = blockIdx.x * 256 + threadIdx.x;   // [0, 131072)
  {
    int i = f & 7, lane = (f >> 3) & 63, jkt = (f >> 9) & 15, ct = f >> 13;
    int c = ct * 16 + (lane & 15);
    int j = jkt * 32 + (lane >> 4) * 8 + i;
    w1[f] = f2b(w[j * CIN + c]);
  }
  {
    int i = f & 7, lane = (f >> 3) & 63, ckt = (f >> 9) & 7, jt = f >> 12;
    int j = jt * 16 + (lane & 15);
    int c = ckt * 32 + (lane >> 4) * 8 + i;
    w2[f] = f2b(w[j * CIN + c]);
  }
}

// Fused NNMF, transposed GEMMs, m-tile-split GEMM2 (acc2 = 32 regs max).
// LDS = 32KB(hB) + 8KB(yF, one m-tile full-K) = 40960 -> 4 blocks/CU.
// No persistent fp32 h: last iteration writes unnormalized fp32 h to out,
// epilogue rescales in place (same-WG L2 RMW, ordered by __syncthreads).
__global__ __launch_bounds__(256, 4) void nnmf_kernel(const float* __restrict__ xin,
                                                      const unsigned short* __restrict__ w1,
                                                      const unsigned short* __restrict__ w2,
                                                      float* __restrict__ redws_all,
                                                      float* __restrict__ out) {
  __shared__ __align__(16) unsigned short hB[2 * 16 * 64 * 8]; // 32 KB
  __shared__ __align__(16) unsigned short yF[8 * 64 * 8];      // 8 KB

  const int tid  = threadIdx.x;
  const int wave = tid >> 6;
  const int lane = tid & 63;
  const int quad = lane >> 4;
  const int col  = lane & 15;

  const int wg     = blockIdx.x;
  const int bb     = wg >> 5;
  const int hwbase = (wg & 31) * 32;
  const float* xbase = xin + (size_t)bb * (CIN * HW) + hwbase;
  float* redws = redws_all + (size_t)wg * 128;   // [m:32][wave:4]
  float* obase = out + (size_t)bb * (COUT * HW) + hwbase;

  // ---- stage x into hB region as u16 [c:256][m:32], coalesced ----
  {
    int m  = tid & 31;
    int c0 = tid >> 5;
#pragma unroll
    for (int g = 0; g < 32; ++g) {
      int c = c0 + (g << 3);
      hB[c * 32 + m] = f2b(xbase[c * HW + m]);
    }
  }
  __syncthreads();

  // ---- gather x: xpk[mt][ci][p] = {x(c0), x(c0+1)}, m=16mt+col, c=16(wave+4ci)+4quad+2p+e ----
  unsigned xpk[2][4][2];
#pragma unroll
  for (int mt = 0; mt < 2; ++mt)
#pragma unroll
    for (int ci = 0; ci < 4; ++ci)
#pragma unroll
      for (int p = 0; p < 2; ++p) {
        int c = ((wave + (ci << 2)) << 4) + (quad << 2) + (p << 1);
        int m = (mt << 4) + col;
        unsigned lo = hB[c * 32 + m];
        unsigned hi = hB[(c + 1) * 32 + m];
        xpk[mt][ci][p] = lo | (hi << 16);
      }
  __syncthreads();

  // ---- init hB = bf16(1/512) (exact; row-sum = 1 -> inv0 = 1) ----
  {
    unsigned* p32 = (unsigned*)hB;
#pragma unroll
    for (int g = 0; g < 32; ++g) p32[tid + (g << 8)] = 0x3B003B00u;
  }
  __syncthreads();

  for (int it = 0; it < ITERS; ++it) {
    // ---- hoisted row-sum loads (consumed after GEMM1) ----
    float rs[2][4];
    if (it) {
      volatile const float* rv = redws;
#pragma unroll
      for (int mt = 0; mt < 2; ++mt)
#pragma unroll
        for (int k = 0; k < 4; ++k) rs[mt][k] = rv[((mt << 4) + col) * 4 + k];
    }

    // ===== GEMM1T: recT[c][m] = sum_j W^T[c][j] h[m][j]; wave ct = wave+4ci =====
    f32x4 acc1[2][4];
#pragma unroll
    for (int mt = 0; mt < 2; ++mt)
#pragma unroll
      for (int ci = 0; ci < 4; ++ci)
#pragma unroll
        for (int r = 0; r < 4; ++r) acc1[mt][ci][r] = 0.0f;

#pragma unroll 2
    for (int jkt = 0; jkt < 16; ++jkt) {
      bf16x8 b0 = *(const bf16x8*)(hB + ((jkt) * 64 + lane) * 8);
      bf16x8 b1 = *(const bf16x8*)(hB + ((16 + jkt) * 64 + lane) * 8);
#pragma unroll
      for (int ci = 0; ci < 4; ++ci) {
        int ct = wave + (ci << 2);
        bf16x8 a = *(const bf16x8*)(w1 + ((ct * 16 + jkt) * 64 + lane) * 8);
        acc1[0][ci] = __builtin_amdgcn_mfma_f32_16x16x32_bf16(a, b0, acc1[0][ci], 0, 0, 0);
        acc1[1][ci] = __builtin_amdgcn_mfma_f32_16x16x32_bf16(a, b1, acc1[1][ci], 0, 0, 0);
      }
    }

    float invv[2];
    if (it) {
#pragma unroll
      for (int mt = 0; mt < 2; ++mt)
        invv[mt] = __builtin_amdgcn_rcpf(rs[mt][0] + rs[mt][1] + rs[mt][2] + rs[mt][3] + 1e-19f);
    } else {
      invv[0] = invv[1] = 1.0f;
    }

    // ===== compute ALL y into packed regs; acc1 dies here =====
    bf16x4 ypk[2][4];
#pragma unroll
    for (int mt = 0; mt < 2; ++mt)
#pragma unroll
      for (int ci = 0; ci < 4; ++ci)
#pragma unroll
        for (int r = 0; r < 4; ++r) {
          float rec = __builtin_fmaf(invv[mt], acc1[mt][ci][r], 1e-20f);
          float xv  = b2f((unsigned short)(xpk[mt][ci][r >> 1] >> ((r & 1) << 4)));
          ypk[mt][ci][r] = (short)f2b(xv * __builtin_amdgcn_rcpf(rec));
        }

    float psum[2] = {0.0f, 0.0f};

    // ===== two m-tile passes: write yF(mt), GEMM2 full-K, h-update(mt) =====
#pragma unroll
    for (int mt = 0; mt < 2; ++mt) {
      // write yF: value y[m=16mt+col][c], c = 16(wave+4ci)+4quad+r
#pragma unroll
      for (int ci = 0; ci < 4; ++ci) {
        int ct = wave + (ci << 2);
        int ckt = ct >> 1;
        int kq = ((ct << 1) + (quad >> 1)) & 3;
        int lane_t = col | (kq << 4);
        int i0 = (quad & 1) << 2;
        *(bf16x4*)(yF + (ckt * 64 + lane_t) * 8 + i0) = ypk[mt][ci];
      }
      __syncthreads();   // yF(mt) ready (mt=0: also all GEMM1 hB reads done)

      // GEMM2T: tT[j][m=16mt+col] = sum_c W[j][c] y[m][c]; wave jt = 8w+n
      f32x4 acc2[8];
#pragma unroll
      for (int n = 0; n < 8; ++n)
#pragma unroll
        for (int r = 0; r < 4; ++r) acc2[n][r] = 0.0f;

#pragma unroll 2
      for (int ckt = 0; ckt < 8; ++ckt) {
        bf16x8 b = *(const bf16x8*)(yF + (ckt * 64 + lane) * 8);
#pragma unroll
        for (int n = 0; n < 8; ++n) {
          int jt = (wave << 3) + n;
          bf16x8 a = *(const bf16x8*)(w2 + ((jt * 8 + ckt) * 64 + lane) * 8);
          acc2[n] = __builtin_amdgcn_mfma_f32_16x16x32_bf16(a, b, acc2[n], 0, 0, 0);
        }
      }

      // h-update: j = 16(8w+n)+4quad+r, m = 16mt+col; exclusive b64 RMW on hB
#pragma unroll
      for (int n = 0; n < 8; ++n) {
        int jkt = (wave << 2) + (n >> 1);
        int lane_t = col | ((((n & 1) << 1) + (quad >> 1)) << 4);
        int i0 = (quad & 1) << 2;
        unsigned short* hp = hB + (((mt << 4) + jkt) * 64 + lane_t) * 8 + i0;
        bf16x4 ho = *(const bf16x4*)hp;
        bf16x4 v;
        float hn0[4];
#pragma unroll
        for (int r = 0; r < 4; ++r) {
          float hn = b2f((unsigned short)ho[r]) * invv[mt] * acc2[n][r];
          hn0[r] = hn;
          psum[mt] += hn;
          v[r] = (short)f2b(hn);
        }
        if (it < ITERS - 1) {
          *(bf16x4*)hp = v;
        } else {
          // final: unnormalized fp32 h -> out (rescaled in epilogue)
          int j = ((((wave << 3) + n) << 4) + (quad << 2));
#pragma unroll
          for (int r = 0; r < 4; ++r)
            obase[(size_t)(j + r) * HW + (mt << 4) + col] = hn0[r];
        }
      }

      if (mt == 1) {
        // cross-quad reduce (lanes col, col+16, col+32, col+48 share pixel m)
#pragma unroll
        for (int m2 = 0; m2 < 2; ++m2) {
          psum[m2] += __shfl_xor(psum[m2], 16, 64);
          psum[m2] += __shfl_xor(psum[m2], 32, 64);
        }
        if (quad == 0) {
          volatile float* rv = redws;
#pragma unroll
          for (int m2 = 0; m2 < 2; ++m2) rv[((m2 << 4) + col) * 4 + wave] = psum[m2];
        }
      }
      __syncthreads();   // mt=0: yF reads done (safe to overwrite); mt=1: hB/red/out ready
    }
  }

  // ---- epilogue: rescale out in place (coalesced; same-WG data only) ----
  float inv;
  {
    int m0 = tid & 31;
    volatile const float* rv = redws;
    float s = rv[m0 * 4 + 0] + rv[m0 * 4 + 1] + rv[m0 * 4 + 2] + rv[m0 * 4 + 3];
    inv = __builtin_amdgcn_rcpf(s + 1e-19f);
  }
  {
    int m0 = tid & 31;
    int j0 = tid >> 5;
#pragma unroll 4
    for (int g = 0; g < 64; ++g) {
      size_t off = (size_t)((g << 3) + j0) * HW + m0;
      obase[off] = obase[off] * inv;
    }
  }
}

extern "C" void kernel_launch(void* const* d_in, const int* in_sizes, int n_in,
                              void* d_out, int out_size, void* d_ws, size_t ws_size,
                              hipStream_t stream) {
  const float* x = (const float*)d_in[0];   // [32,256,32,32]
  const float* w = (const float*)d_in[1];   // [512,256]
  unsigned short* w1 = (unsigned short*)d_ws;           // 256 KB
  unsigned short* w2 = w1 + COUT * CIN;                 // 256 KB
  float* red = (float*)(w2 + COUT * CIN);               // 512 KB
  float* out = (float*)d_out;

  prep_weights<<<dim3(512), dim3(256), 0, stream>>>(w, w1, w2);
  nnmf_kernel<<<dim3(32768 / 32), dim3(256), 0, stream>>>(x, w1, w2, red, out);
}